// Round 3
// baseline (967.267 us; speedup 1.0000x reference)
//
#include <hip/hip_runtime.h>

// Problem constants (B=8, S=2048, D=1024, H=4096, E=8, CAP_FACTOR=1.5)
#define NTOK 16384
#define DDIM 1024
#define EEXP 8
#define HDIM 4096
#define CAP  3072               // int(1.5 * 16384 / 8)
#define ECAP (EEXP*CAP)         // 24576
#define RT_PER_E (CAP/128)      // 24 row-tiles per expert

// Workspace layout (bytes)
#define OFF_GATE 0u                          // float[NTOK]
#define OFF_GIDX 65536u                      // int[NTOK]
#define OFF_SLOT 131072u                     // int[NTOK]
#define OFF_TOS  196608u                     // int[ECAP]
#define OFF_CNT  294912u                     // int[8]
#define OFF_PIMP 294976u                     // float[4096*8]
#define OFF_XBF  1048576u                    // ushort[NTOK*DDIM]       (32 MB)
#define OFF_W1T  34603008u                   // ushort[E*HDIM*DDIM]     (64 MB) [e][n][k]
#define OFF_W2T  101711872u                  // ushort[E*DDIM*HDIM]     (64 MB) [e][n][k]
#define OFF_HB   168820736u                  // ushort[ECAP*HDIM]       (192 MB)

typedef float f32x4  __attribute__((ext_vector_type(4)));
typedef short bf16x8 __attribute__((ext_vector_type(8)));

__device__ __forceinline__ unsigned short f2bf(float f){
  unsigned int u = __float_as_uint(f);
  unsigned int r = (u + 0x7fffu + ((u >> 16) & 1u)) >> 16;   // RNE
  return (unsigned short)r;
}
__device__ __forceinline__ float siluf(float v){ return v/(1.0f+__expf(-v)); }

// async global->LDS, 16B per lane; LDS dst is wave-uniform base + lane*16
__device__ __forceinline__ void gl16(const void* g, void* l){
  __builtin_amdgcn_global_load_lds((const __attribute__((address_space(1))) unsigned int*)g,
                                   (__attribute__((address_space(3))) unsigned int*)l,
                                   16, 0, 0);
}

// ---------------------------------------------------------------------------
// Router: one wave per token. Also emits x in bf16 (fused conversion).
// ---------------------------------------------------------------------------
__global__ __launch_bounds__(256) void router_kernel(
    const float* __restrict__ x, const float* __restrict__ Wr,
    const float* __restrict__ br, float* __restrict__ gate_value,
    int* __restrict__ gate_idx, float* __restrict__ partial_imp,
    unsigned short* __restrict__ xbf)
{
  __shared__ float pbuf[4][8];
  const int wave = threadIdx.x >> 6;
  const int lane = threadIdx.x & 63;
  const int n = blockIdx.x*4 + wave;
  float acc[8];
#pragma unroll
  for (int e=0;e<8;e++) acc[e]=0.0f;
  const float* xr = x + (size_t)n*DDIM;
  unsigned short* xbr = xbf + (size_t)n*DDIM;
#pragma unroll
  for (int k=0;k<16;k++){
    const int d = k*64 + lane;
    const float xv = xr[d];
    xbr[d] = f2bf(xv);
    const float4 w0 = ((const float4*)(Wr + (size_t)d*8))[0];
    const float4 w1 = ((const float4*)(Wr + (size_t)d*8))[1];
    acc[0] += xv*w0.x; acc[1] += xv*w0.y; acc[2] += xv*w0.z; acc[3] += xv*w0.w;
    acc[4] += xv*w1.x; acc[5] += xv*w1.y; acc[6] += xv*w1.z; acc[7] += xv*w1.w;
  }
#pragma unroll
  for (int e=0;e<8;e++){
    acc[e] += __shfl_xor(acc[e], 32, 64);
    acc[e] += __shfl_xor(acc[e], 16, 64);
    acc[e] += __shfl_xor(acc[e],  8, 64);
    acc[e] += __shfl_xor(acc[e],  4, 64);
    acc[e] += __shfl_xor(acc[e],  2, 64);
    acc[e] += __shfl_xor(acc[e],  1, 64);
  }
  if (lane==0){
    float lg[8];
    float mx = -3.4e38f;
    int bi = 0;
#pragma unroll
    for (int e=0;e<8;e++) lg[e] = acc[e] + br[e];
#pragma unroll
    for (int e=0;e<8;e++){ if (lg[e] > mx){ mx = lg[e]; bi = e; } }
    float s = 0.f;
#pragma unroll
    for (int e=0;e<8;e++){ lg[e] = __expf(lg[e]-mx); s += lg[e]; }
    const float inv = 1.0f/s;
    gate_value[n] = inv;
    gate_idx[n] = bi;
#pragma unroll
    for (int e=0;e<8;e++) pbuf[wave][e] = lg[e]*inv;
  }
  __syncthreads();
  if (threadIdx.x < 8){
    partial_imp[(size_t)blockIdx.x*8 + threadIdx.x] =
      pbuf[0][threadIdx.x]+pbuf[1][threadIdx.x]+pbuf[2][threadIdx.x]+pbuf[3][threadIdx.x];
  }
}

// ---------------------------------------------------------------------------
// Scan: FIFO positions per expert (single block) + aux losses.
// Bit-packed per-thread counters (8 experts x 8 bits) -> no scratch arrays.
// ---------------------------------------------------------------------------
__global__ __launch_bounds__(256) void scan_kernel(
    const int* __restrict__ gate_idx, const float* __restrict__ partial_imp,
    int* __restrict__ slot_or_neg, int* __restrict__ tok_of_slot,
    int* __restrict__ cnt, float* __restrict__ out_losses)
{
  __shared__ int hist[256][8];
  __shared__ float impbuf[32][8];
  const int t = threadIdx.x;
  const int4* gp = (const int4*)(gate_idx + t*64);

  unsigned long long pk = 0;
#pragma unroll 4
  for (int i=0;i<16;i++){
    const int4 v = gp[i];
    pk += (1ull<<(v.x<<3)) + (1ull<<(v.y<<3)) + (1ull<<(v.z<<3)) + (1ull<<(v.w<<3));
  }
#pragma unroll
  for (int e=0;e<8;e++) hist[t][e] = (int)((pk>>(e<<3)) & 0xffull);
  {
    const int e = t & 7, c = t >> 3;
    float s = 0.f;
    for (int r=c; r<4096; r+=32) s += partial_imp[(size_t)r*8+e];
    impbuf[c][e] = s;
  }
  __syncthreads();
  if (t < 8){
    int run = 0;
    for (int i=0;i<256;i++){ const int v = hist[i][t]; hist[i][t] = run; run += v; }
    cnt[t] = run < CAP ? run : CAP;
  }
  __syncthreads();
  pk = 0;
  for (int i=0;i<16;i++){
    const int4 v = gp[i];
    const int ids[4] = {v.x, v.y, v.z, v.w};
#pragma unroll
    for (int j=0;j<4;j++){
      const int n = t*64 + i*4 + j;
      const int e = ids[j];
      const int p = hist[t][e] + (int)((pk>>(e<<3)) & 0xffull);
      pk += 1ull<<(e<<3);
      if (p < CAP){ const int s = e*CAP+p; slot_or_neg[n]=s; tok_of_slot[s]=n; }
      else slot_or_neg[n] = -1;
    }
  }
  if (t==0){
    float imp[8]; float m = 0.f;
    for (int e=0;e<8;e++){ float s=0.f; for (int c=0;c<32;c++) s+=impbuf[c][e]; imp[e]=s; m+=s; }
    m *= 0.125f;
    float var = 0.f;
    for (int e=0;e<8;e++){ const float d=imp[e]-m; var += d*d; }
    var *= 0.125f;
    out_losses[0] = 1.0f;
    out_losses[1] = var/(m*m);
  }
}

// ---------------------------------------------------------------------------
// Weight transpose + fp32->bf16: W [E][K][N] -> Wt [E][N][K].
// ---------------------------------------------------------------------------
__global__ __launch_bounds__(256) void cvt_w_t(
    const float* __restrict__ W, unsigned short* __restrict__ Wt, int K, int N)
{
  __shared__ float t[32][33];
  const int e = blockIdx.z;
  const int n0 = blockIdx.x*32, k0 = blockIdx.y*32;
  const int r = threadIdx.x>>3, c4 = (threadIdx.x&7)*4;
  const float4 v = *(const float4*)(W + ((size_t)e*K + k0 + r)*N + n0 + c4);
  t[r][c4+0]=v.x; t[r][c4+1]=v.y; t[r][c4+2]=v.z; t[r][c4+3]=v.w;
  __syncthreads();
  ushort4 o;
  o.x = f2bf(t[c4+0][r]); o.y = f2bf(t[c4+1][r]);
  o.z = f2bf(t[c4+2][r]); o.w = f2bf(t[c4+3][r]);
  *(ushort4*)(Wt + ((size_t)e*N + n0 + r)*K + k0 + c4) = o;
}

// ---------------------------------------------------------------------------
// MFMA grouped FFN GEMM, 2-stage software pipeline.
// 128x128 tile, BK=32 bf16, 4 waves, wave 64x64 via 4x4 mfma_f32_16x16x32_bf16.
// LDS double-buffered (2 x 16 KB): next K-step's global_load_lds issued right
// after the ready-barrier, BEFORE compute -> the compiler's vmcnt(0) drain at
// the next barrier waits on loads that already had a compute phase in flight.
// XOR-swizzled 16B chunks: chunk(r,kg) at r*64 + (kg ^ ((r>>1)&3))*16.
// Grid is TRANSPOSED (x=rowtile): all coltiles of one rowtile share flat%8
// -> same XCD -> A-tile fetched once per XCD L2.
// ---------------------------------------------------------------------------
template<int PHASE>
__global__ __launch_bounds__(256) void ffn_mfma(
    const unsigned short* __restrict__ A,   // PHASE1: xbf [NTOK][1024]; PHASE2: hbf [ECAP][4096]
    const unsigned short* __restrict__ Bt,  // [E][NN][K] k-contiguous
    const float* __restrict__ bias,         // [E][NN]
    const int* __restrict__ tok_of_slot,
    const int* __restrict__ cnt,
    const float* __restrict__ gate_value,
    void* __restrict__ Out)
{
  constexpr int K  = (PHASE==1)? DDIM : HDIM;
  constexpr int NN = (PHASE==1)? HDIM : DDIM;
  const int rowtile = blockIdx.x;           // transposed grid (XCD co-location)
  const int coltile = blockIdx.y;
  const int e  = rowtile / RT_PER_E;
  const int r0 = (rowtile - e*RT_PER_E)*128;
  const int ce = cnt[e];
  if (r0 >= ce) return;                     // block-uniform early exit

  __shared__ alignas(16) char smem[32768];  // 2 buffers x (A 8K + B 8K)

  const int tid  = threadIdx.x;
  const int l    = tid & 63;
  const int wv   = __builtin_amdgcn_readfirstlane(tid >> 6);

  // ---- staging addresses (2 A chunks + 2 B chunks per lane per K-step)
  const int sub = l >> 2;                   // 0..15
  const int c   = l & 3;
  const int gr0 = wv*16 + sub;              // tile rows 0..63
  const int gr1 = 64 + gr0;                 // tile rows 64..127
  const int kg0 = c ^ ((gr0>>1)&3);
  const int kg1 = c ^ ((gr1>>1)&3);

  const unsigned short *agp0, *agp1;
  if (PHASE==1){
    const int t0 = (r0 + gr0 < ce) ? tok_of_slot[rowtile*128 + gr0] : 0;
    const int t1 = (r0 + gr1 < ce) ? tok_of_slot[rowtile*128 + gr1] : 0;
    agp0 = A + (size_t)t0*K + kg0*8;
    agp1 = A + (size_t)t1*K + kg1*8;
  } else {
    agp0 = A + (size_t)(rowtile*128 + gr0)*K + kg0*8;
    agp1 = A + (size_t)(rowtile*128 + gr1)*K + kg1*8;
  }
  const unsigned short* bgp0 = Bt + ((size_t)e*NN + coltile*128 + gr0)*K + kg0*8;
  const unsigned short* bgp1 = Bt + ((size_t)e*NN + coltile*128 + gr1)*K + kg1*8;

  // ---- fragment read offsets (within one 16 KB buffer)
  const int wrow = (wv & 1)*64, wcol = (wv >> 1)*64;
  const int lm  = l & 15;
  const int kgf = l >> 4;                   // 0..3
  int aoff[4], boff[4];
#pragma unroll
  for (int i=0;i<4;i++){
    const int ra = wrow + i*16 + lm;
    aoff[i] = ra*64 + ((kgf ^ ((ra>>1)&3))*16);
    const int rb = wcol + i*16 + lm;
    boff[i] = rb*64 + ((kgf ^ ((rb>>1)&3))*16) + 8192;
  }

  f32x4 acc[4][4];
#pragma unroll
  for (int i=0;i<4;i++)
#pragma unroll
    for (int j=0;j<4;j++) acc[i][j] = (f32x4){0.f,0.f,0.f,0.f};

  auto stage = [&](int k0, int b){
    char* base = smem + (b<<14) + (wv<<10);
    gl16(agp0 + k0, base);
    gl16(agp1 + k0, base + 4096);
    gl16(bgp0 + k0, base + 8192);
    gl16(bgp1 + k0, base + 12288);
  };
  auto compute = [&](int b){
    const char* base = smem + (b<<14);
    bf16x8 af[4], bf[4];
#pragma unroll
    for (int i=0;i<4;i++) af[i] = *(const bf16x8*)(base + aoff[i]);
#pragma unroll
    for (int i=0;i<4;i++) bf[i] = *(const bf16x8*)(base + boff[i]);
#pragma unroll
    for (int mi=0;mi<4;mi++)
#pragma unroll
      for (int ni=0;ni<4;ni++)
        acc[mi][ni] = __builtin_amdgcn_mfma_f32_16x16x32_bf16(af[mi], bf[ni], acc[mi][ni], 0, 0, 0);
  };

  stage(0, 0);
  for (int k0 = 0; k0 < K; k0 += 64){
    __syncthreads();                        // drains buf0 loads (issued one compute-phase ago)
    stage(k0+32, 1);                        // prefetch next half into buf1
    compute(0);
    __syncthreads();                        // drains buf1 loads
    if (k0+64 < K) stage(k0+64, 0);
    compute(1);
  }

  // ---- epilogue. C/D layout: col = lane&15, row = (lane>>4)*4 + reg
  const float* bp = bias + (size_t)e*NN + coltile*128 + wcol;
  float bv[4];
#pragma unroll
  for (int ni=0;ni<4;ni++) bv[ni] = bp[ni*16 + lm];

  if (PHASE==1){
    unsigned short* hb = (unsigned short*)Out;
#pragma unroll
    for (int mi=0;mi<4;mi++){
#pragma unroll
      for (int r=0;r<4;r++){
        const int row = wrow + mi*16 + kgf*4 + r;
        unsigned short* hr = hb + (size_t)(rowtile*128 + row)*NN + coltile*128 + wcol;
#pragma unroll
        for (int ni=0;ni<4;ni++){
          const float v = acc[mi][ni][r] + bv[ni];
          hr[ni*16 + lm] = f2bf(siluf(v));
        }
      }
    }
  } else {
    float* op = (float*)Out;
#pragma unroll
    for (int mi=0;mi<4;mi++){
#pragma unroll
      for (int r=0;r<4;r++){
        const int row = wrow + mi*16 + kgf*4 + r;
        if (r0 + row < ce){
          const int tok = tok_of_slot[rowtile*128 + row];
          const float g = gate_value[tok];
          float* orow = op + (size_t)tok*NN + coltile*128 + wcol;
#pragma unroll
          for (int ni=0;ni<4;ni++)
            orow[ni*16 + lm] = (acc[mi][ni][r] + bv[ni])*g;
        }
      }
    }
  }
}

// ---------------------------------------------------------------------------
// Dropped tokens pass through: out[n] = x[n] * gate[n]
// ---------------------------------------------------------------------------
__global__ __launch_bounds__(256) void passthrough_kernel(
    const float* __restrict__ x, const int* __restrict__ slot_or_neg,
    const float* __restrict__ gate_value, float* __restrict__ out)
{
  const int n = blockIdx.x;
  if (slot_or_neg[n] >= 0) return;
  const float g = gate_value[n];
  float4 v = *(const float4*)(x + (size_t)n*DDIM + threadIdx.x*4);
  v.x*=g; v.y*=g; v.z*=g; v.w*=g;
  *(float4*)(out + (size_t)n*DDIM + threadIdx.x*4) = v;
}

extern "C" void kernel_launch(void* const* d_in, const int* in_sizes, int n_in,
                              void* d_out, int out_size, void* d_ws, size_t ws_size,
                              hipStream_t stream)
{
  const float* x  = (const float*)d_in[0];
  const float* Wr = (const float*)d_in[1];
  const float* br = (const float*)d_in[2];
  const float* W1 = (const float*)d_in[3];
  const float* b1 = (const float*)d_in[4];
  const float* W2 = (const float*)d_in[5];
  const float* b2 = (const float*)d_in[6];
  float* out = (float*)d_out;

  char* ws = (char*)d_ws;
  float*          gate_value  = (float*)(ws + OFF_GATE);
  int*            gate_idx    = (int*)  (ws + OFF_GIDX);
  int*            slot_or_neg = (int*)  (ws + OFF_SLOT);
  int*            tok_of_slot = (int*)  (ws + OFF_TOS);
  int*            cnt         = (int*)  (ws + OFF_CNT);
  float*          partial_imp = (float*)(ws + OFF_PIMP);
  unsigned short* xbf         = (unsigned short*)(ws + OFF_XBF);
  unsigned short* W1t         = (unsigned short*)(ws + OFF_W1T);
  unsigned short* W2t         = (unsigned short*)(ws + OFF_W2T);
  unsigned short* hbf         = (unsigned short*)(ws + OFF_HB);

  cvt_w_t<<<dim3(HDIM/32, DDIM/32, EEXP), 256, 0, stream>>>(W1, W1t, DDIM, HDIM);
  cvt_w_t<<<dim3(DDIM/32, HDIM/32, EEXP), 256, 0, stream>>>(W2, W2t, HDIM, DDIM);

  router_kernel<<<NTOK/4, 256, 0, stream>>>(x, Wr, br, gate_value, gate_idx,
                                            partial_imp, xbf);
  scan_kernel<<<1, 256, 0, stream>>>(gate_idx, partial_imp, slot_or_neg, tok_of_slot,
                                     cnt, out + (size_t)NTOK*DDIM);

  // transposed grids: x = rowtile (192), y = coltile
  ffn_mfma<1><<<dim3(ECAP/128, HDIM/128), 256, 0, stream>>>(
      xbf, W1t, b1, tok_of_slot, cnt, gate_value, (void*)hbf);
  ffn_mfma<2><<<dim3(ECAP/128, DDIM/128), 256, 0, stream>>>(
      hbf, W2t, b2, tok_of_slot, cnt, gate_value, (void*)out);

  passthrough_kernel<<<NTOK, 256, 0, stream>>>(x, slot_or_neg, gate_value, out);
}

// Round 4
// 923.188 us; speedup vs baseline: 1.0477x; 1.0477x over previous
//
#include <hip/hip_runtime.h>

// Problem constants (B=8, S=2048, D=1024, H=4096, E=8, CAP_FACTOR=1.5)
#define NTOK 16384
#define DDIM 1024
#define EEXP 8
#define HDIM 4096
#define CAP  3072               // int(1.5 * 16384 / 8)
#define ECAP (EEXP*CAP)         // 24576
#define RT_PER_E (CAP/128)      // 24 row-tiles per expert

// Workspace layout (bytes)
#define OFF_GATE 0u                          // float[NTOK]
#define OFF_GIDX 65536u                      // int[NTOK]
#define OFF_SLOT 131072u                     // int[NTOK]
#define OFF_TOS  196608u                     // int[ECAP]
#define OFF_CNT  294912u                     // int[8]
#define OFF_PIMP 294976u                     // float[4096*8]
#define OFF_XBF  1048576u                    // ushort[NTOK*DDIM]       (32 MB)
#define OFF_W1T  34603008u                   // ushort[E*HDIM*DDIM]     (64 MB) [e][n][k]
#define OFF_W2T  101711872u                  // ushort[E*DDIM*HDIM]     (64 MB) [e][n][k]
#define OFF_HB   168820736u                  // ushort[ECAP*HDIM]       (192 MB)

typedef float f32x4  __attribute__((ext_vector_type(4)));
typedef short bf16x8 __attribute__((ext_vector_type(8)));

__device__ __forceinline__ unsigned short f2bf(float f){
  unsigned int u = __float_as_uint(f);
  unsigned int r = (u + 0x7fffu + ((u >> 16) & 1u)) >> 16;   // RNE
  return (unsigned short)r;
}
__device__ __forceinline__ float siluf(float v){ return v/(1.0f+__expf(-v)); }

// async global->LDS, 16B per lane; LDS dst is wave-uniform base + lane*16
__device__ __forceinline__ void gl16(const void* g, void* l){
  __builtin_amdgcn_global_load_lds((const __attribute__((address_space(1))) unsigned int*)g,
                                   (__attribute__((address_space(3))) unsigned int*)l,
                                   16, 0, 0);
}

// ---------------------------------------------------------------------------
// Router: one wave per token. Also emits x in bf16 (fused conversion).
// ---------------------------------------------------------------------------
__global__ __launch_bounds__(256) void router_kernel(
    const float* __restrict__ x, const float* __restrict__ Wr,
    const float* __restrict__ br, float* __restrict__ gate_value,
    int* __restrict__ gate_idx, float* __restrict__ partial_imp,
    unsigned short* __restrict__ xbf)
{
  __shared__ float pbuf[4][8];
  const int wave = threadIdx.x >> 6;
  const int lane = threadIdx.x & 63;
  const int n = blockIdx.x*4 + wave;
  float acc[8];
#pragma unroll
  for (int e=0;e<8;e++) acc[e]=0.0f;
  const float* xr = x + (size_t)n*DDIM;
  unsigned short* xbr = xbf + (size_t)n*DDIM;
#pragma unroll
  for (int k=0;k<16;k++){
    const int d = k*64 + lane;
    const float xv = xr[d];
    xbr[d] = f2bf(xv);
    const float4 w0 = ((const float4*)(Wr + (size_t)d*8))[0];
    const float4 w1 = ((const float4*)(Wr + (size_t)d*8))[1];
    acc[0] += xv*w0.x; acc[1] += xv*w0.y; acc[2] += xv*w0.z; acc[3] += xv*w0.w;
    acc[4] += xv*w1.x; acc[5] += xv*w1.y; acc[6] += xv*w1.z; acc[7] += xv*w1.w;
  }
#pragma unroll
  for (int e=0;e<8;e++){
    acc[e] += __shfl_xor(acc[e], 32, 64);
    acc[e] += __shfl_xor(acc[e], 16, 64);
    acc[e] += __shfl_xor(acc[e],  8, 64);
    acc[e] += __shfl_xor(acc[e],  4, 64);
    acc[e] += __shfl_xor(acc[e],  2, 64);
    acc[e] += __shfl_xor(acc[e],  1, 64);
  }
  if (lane==0){
    float lg[8];
    float mx = -3.4e38f;
    int bi = 0;
#pragma unroll
    for (int e=0;e<8;e++) lg[e] = acc[e] + br[e];
#pragma unroll
    for (int e=0;e<8;e++){ if (lg[e] > mx){ mx = lg[e]; bi = e; } }
    float s = 0.f;
#pragma unroll
    for (int e=0;e<8;e++){ lg[e] = __expf(lg[e]-mx); s += lg[e]; }
    const float inv = 1.0f/s;
    gate_value[n] = inv;
    gate_idx[n] = bi;
#pragma unroll
    for (int e=0;e<8;e++) pbuf[wave][e] = lg[e]*inv;
  }
  __syncthreads();
  if (threadIdx.x < 8){
    partial_imp[(size_t)blockIdx.x*8 + threadIdx.x] =
      pbuf[0][threadIdx.x]+pbuf[1][threadIdx.x]+pbuf[2][threadIdx.x]+pbuf[3][threadIdx.x];
  }
}

// ---------------------------------------------------------------------------
// Scan: FIFO positions per expert (single block) + aux losses.
// Bit-packed per-thread counters (8 experts x 8 bits) -> no scratch arrays.
// ---------------------------------------------------------------------------
__global__ __launch_bounds__(256) void scan_kernel(
    const int* __restrict__ gate_idx, const float* __restrict__ partial_imp,
    int* __restrict__ slot_or_neg, int* __restrict__ tok_of_slot,
    int* __restrict__ cnt, float* __restrict__ out_losses)
{
  __shared__ int hist[256][8];
  __shared__ float impbuf[32][8];
  const int t = threadIdx.x;
  const int4* gp = (const int4*)(gate_idx + t*64);

  unsigned long long pk = 0;
#pragma unroll 4
  for (int i=0;i<16;i++){
    const int4 v = gp[i];
    pk += (1ull<<(v.x<<3)) + (1ull<<(v.y<<3)) + (1ull<<(v.z<<3)) + (1ull<<(v.w<<3));
  }
#pragma unroll
  for (int e=0;e<8;e++) hist[t][e] = (int)((pk>>(e<<3)) & 0xffull);
  {
    const int e = t & 7, c = t >> 3;
    float s = 0.f;
    for (int r=c; r<4096; r+=32) s += partial_imp[(size_t)r*8+e];
    impbuf[c][e] = s;
  }
  __syncthreads();
  if (t < 8){
    int run = 0;
    for (int i=0;i<256;i++){ const int v = hist[i][t]; hist[i][t] = run; run += v; }
    cnt[t] = run < CAP ? run : CAP;
  }
  __syncthreads();
  pk = 0;
  for (int i=0;i<16;i++){
    const int4 v = gp[i];
    const int ids[4] = {v.x, v.y, v.z, v.w};
#pragma unroll
    for (int j=0;j<4;j++){
      const int n = t*64 + i*4 + j;
      const int e = ids[j];
      const int p = hist[t][e] + (int)((pk>>(e<<3)) & 0xffull);
      pk += 1ull<<(e<<3);
      if (p < CAP){ const int s = e*CAP+p; slot_or_neg[n]=s; tok_of_slot[s]=n; }
      else slot_or_neg[n] = -1;
    }
  }
  if (t==0){
    float imp[8]; float m = 0.f;
    for (int e=0;e<8;e++){ float s=0.f; for (int c=0;c<32;c++) s+=impbuf[c][e]; imp[e]=s; m+=s; }
    m *= 0.125f;
    float var = 0.f;
    for (int e=0;e<8;e++){ const float d=imp[e]-m; var += d*d; }
    var *= 0.125f;
    out_losses[0] = 1.0f;
    out_losses[1] = var/(m*m);
  }
}

// ---------------------------------------------------------------------------
// Weight transpose + fp32->bf16: W [E][K][N] -> Wt [E][N][K].
// ---------------------------------------------------------------------------
__global__ __launch_bounds__(256) void cvt_w_t(
    const float* __restrict__ W, unsigned short* __restrict__ Wt, int K, int N)
{
  __shared__ float t[32][33];
  const int e = blockIdx.z;
  const int n0 = blockIdx.x*32, k0 = blockIdx.y*32;
  const int r = threadIdx.x>>3, c4 = (threadIdx.x&7)*4;
  const float4 v = *(const float4*)(W + ((size_t)e*K + k0 + r)*N + n0 + c4);
  t[r][c4+0]=v.x; t[r][c4+1]=v.y; t[r][c4+2]=v.z; t[r][c4+3]=v.w;
  __syncthreads();
  ushort4 o;
  o.x = f2bf(t[c4+0][r]); o.y = f2bf(t[c4+1][r]);
  o.z = f2bf(t[c4+2][r]); o.w = f2bf(t[c4+3][r]);
  *(ushort4*)(Wt + ((size_t)e*N + n0 + r)*K + k0 + c4) = o;
}

// ---------------------------------------------------------------------------
// MFMA grouped FFN GEMM — R2 structure, BK=64 (one barrier-pair per 64 K).
// 128x128 tile, 4 waves, wave 64x64 via 4x4 mfma_f32_16x16x32_bf16, 2 k-halves.
// LDS single buffer 32 KB: A 128 rows x 64 bf16 (128 B rows, 8 chunks of 16B),
// B same at +16K. Chunk kg of row r stored at slot kg^(r&7) -> fragment
// ds_read_b128 is ≤2-way (free); staging is contiguous per gl16 (1 KB/wave).
// Per K-step per wave: 8 gl16-equiv staged bytes across block, 16 ds_read_b128,
// 32 MFMA between barriers (AITER-like MFMA:barrier ratio).
// ---------------------------------------------------------------------------
template<int PHASE>
__global__ __launch_bounds__(256) void ffn_mfma(
    const unsigned short* __restrict__ A,   // PHASE1: xbf [NTOK][1024]; PHASE2: hbf [ECAP][4096]
    const unsigned short* __restrict__ Bt,  // [E][NN][K] k-contiguous
    const float* __restrict__ bias,         // [E][NN]
    const int* __restrict__ tok_of_slot,
    const int* __restrict__ cnt,
    const float* __restrict__ gate_value,
    void* __restrict__ Out)
{
  constexpr int K  = (PHASE==1)? DDIM : HDIM;
  constexpr int NN = (PHASE==1)? HDIM : DDIM;
  const int rowtile = blockIdx.y;
  const int coltile = blockIdx.x;
  const int e  = rowtile / RT_PER_E;
  const int r0 = (rowtile - e*RT_PER_E)*128;
  const int ce = cnt[e];
  if (r0 >= ce) return;                     // block-uniform early exit

  __shared__ alignas(16) char smem[32768];  // A 16K | B 16K
  char* As  = smem;
  char* Bsm = smem + 16384;

  const int tid  = threadIdx.x;
  const int l    = tid & 63;
  const int wv   = __builtin_amdgcn_readfirstlane(tid >> 6);

  // ---- staging: wave wv covers tile rows [wv*32, wv*32+32) of A and of B.
  // gl16 #i (i=0..3) writes LDS rows wv*32+i*8 .. +8 (1 KB contiguous).
  // lane l -> row sub rl = l>>3, slot s = l&7, stored k-chunk kg = s ^ rl.
  const int rl = l >> 3;                    // 0..7
  const int kg = (l & 7) ^ rl;              // k-chunk this lane fetches
  const int growA = wv*32 + rl;             // + i*8

  const unsigned short* agp[4];
#pragma unroll
  for (int i=0;i<4;i++){
    const int gr = growA + i*8;             // tile row 0..127
    if (PHASE==1){
      const int t0 = (r0 + gr < ce) ? tok_of_slot[rowtile*128 + gr] : 0;
      agp[i] = A + (size_t)t0*K + kg*8;
    } else {
      agp[i] = A + (size_t)(rowtile*128 + gr)*K + kg*8;
    }
  }
  const unsigned short* bgp = Bt + ((size_t)e*NN + coltile*128 + growA)*K + kg*8;

  char* a_dst = As  + (wv<<12);
  char* b_dst = Bsm + (wv<<12);

  // ---- fragment read offsets. Row r, k-half h, k-group kgf: chunk c=h*4+kgf
  // at byte r*128 + ((c ^ (r&7))*16); r&7 == lm&7 for all mi (wrow, mi*16 are
  // multiples of 8).
  const int wrow = (wv & 1)*64, wcol = (wv >> 1)*64;
  const int lm  = l & 15;
  const int kgf = l >> 4;                   // 0..3
  const int m7  = lm & 7;
  int aoff[2][4], boff[2][4];
#pragma unroll
  for (int i=0;i<4;i++){
    const int ra = wrow + i*16 + lm;
    const int rb = wcol + i*16 + lm;
    const int c0 = (kgf ^ m7)*16;
    aoff[0][i] = ra*128 + c0;       aoff[1][i] = ra*128 + (c0 ^ 64);
    boff[0][i] = rb*128 + c0;       boff[1][i] = rb*128 + (c0 ^ 64);
  }

  f32x4 acc[4][4];
#pragma unroll
  for (int i=0;i<4;i++)
#pragma unroll
    for (int j=0;j<4;j++) acc[i][j] = (f32x4){0.f,0.f,0.f,0.f};

  for (int k0 = 0; k0 < K; k0 += 64){
    __syncthreads();                        // prev step done reading LDS
#pragma unroll
    for (int i=0;i<4;i++){
      gl16(agp[i] + k0,       a_dst + i*1024);
      gl16(bgp + i*8*K + k0,  b_dst + i*1024);
    }
    __syncthreads();                        // staging visible
#pragma unroll
    for (int h=0; h<2; h++){
      bf16x8 af[4], bf[4];
#pragma unroll
      for (int i=0;i<4;i++) af[i] = *(const bf16x8*)(As  + aoff[h][i]);
#pragma unroll
      for (int i=0;i<4;i++) bf[i] = *(const bf16x8*)(Bsm + boff[h][i]);
#pragma unroll
      for (int mi=0;mi<4;mi++)
#pragma unroll
        for (int ni=0;ni<4;ni++)
          acc[mi][ni] = __builtin_amdgcn_mfma_f32_16x16x32_bf16(af[mi], bf[ni], acc[mi][ni], 0, 0, 0);
    }
  }

  // ---- epilogue. C/D layout: col = lane&15, row = (lane>>4)*4 + reg
  const float* bp = bias + (size_t)e*NN + coltile*128 + wcol;
  float bv[4];
#pragma unroll
  for (int ni=0;ni<4;ni++) bv[ni] = bp[ni*16 + lm];

  if (PHASE==1){
    unsigned short* hb = (unsigned short*)Out;
#pragma unroll
    for (int mi=0;mi<4;mi++){
#pragma unroll
      for (int r=0;r<4;r++){
        const int row = wrow + mi*16 + kgf*4 + r;
        unsigned short* hr = hb + (size_t)(rowtile*128 + row)*NN + coltile*128 + wcol;
#pragma unroll
        for (int ni=0;ni<4;ni++){
          const float v = acc[mi][ni][r] + bv[ni];
          hr[ni*16 + lm] = f2bf(siluf(v));
        }
      }
    }
  } else {
    float* op = (float*)Out;
#pragma unroll
    for (int mi=0;mi<4;mi++){
#pragma unroll
      for (int r=0;r<4;r++){
        const int row = wrow + mi*16 + kgf*4 + r;
        if (r0 + row < ce){
          const int tok = tok_of_slot[rowtile*128 + row];
          const float g = gate_value[tok];
          float* orow = op + (size_t)tok*NN + coltile*128 + wcol;
#pragma unroll
          for (int ni=0;ni<4;ni++)
            orow[ni*16 + lm] = (acc[mi][ni][r] + bv[ni])*g;
        }
      }
    }
  }
}

// ---------------------------------------------------------------------------
// Dropped tokens pass through: out[n] = x[n] * gate[n]
// ---------------------------------------------------------------------------
__global__ __launch_bounds__(256) void passthrough_kernel(
    const float* __restrict__ x, const int* __restrict__ slot_or_neg,
    const float* __restrict__ gate_value, float* __restrict__ out)
{
  const int n = blockIdx.x;
  if (slot_or_neg[n] >= 0) return;
  const float g = gate_value[n];
  float4 v = *(const float4*)(x + (size_t)n*DDIM + threadIdx.x*4);
  v.x*=g; v.y*=g; v.z*=g; v.w*=g;
  *(float4*)(out + (size_t)n*DDIM + threadIdx.x*4) = v;
}

extern "C" void kernel_launch(void* const* d_in, const int* in_sizes, int n_in,
                              void* d_out, int out_size, void* d_ws, size_t ws_size,
                              hipStream_t stream)
{
  const float* x  = (const float*)d_in[0];
  const float* Wr = (const float*)d_in[1];
  const float* br = (const float*)d_in[2];
  const float* W1 = (const float*)d_in[3];
  const float* b1 = (const float*)d_in[4];
  const float* W2 = (const float*)d_in[5];
  const float* b2 = (const float*)d_in[6];
  float* out = (float*)d_out;

  char* ws = (char*)d_ws;
  float*          gate_value  = (float*)(ws + OFF_GATE);
  int*            gate_idx    = (int*)  (ws + OFF_GIDX);
  int*            slot_or_neg = (int*)  (ws + OFF_SLOT);
  int*            tok_of_slot = (int*)  (ws + OFF_TOS);
  int*            cnt         = (int*)  (ws + OFF_CNT);
  float*          partial_imp = (float*)(ws + OFF_PIMP);
  unsigned short* xbf         = (unsigned short*)(ws + OFF_XBF);
  unsigned short* W1t         = (unsigned short*)(ws + OFF_W1T);
  unsigned short* W2t         = (unsigned short*)(ws + OFF_W2T);
  unsigned short* hbf         = (unsigned short*)(ws + OFF_HB);

  cvt_w_t<<<dim3(HDIM/32, DDIM/32, EEXP), 256, 0, stream>>>(W1, W1t, DDIM, HDIM);
  cvt_w_t<<<dim3(DDIM/32, HDIM/32, EEXP), 256, 0, stream>>>(W2, W2t, HDIM, DDIM);

  router_kernel<<<NTOK/4, 256, 0, stream>>>(x, Wr, br, gate_value, gate_idx,
                                            partial_imp, xbf);
  scan_kernel<<<1, 256, 0, stream>>>(gate_idx, partial_imp, slot_or_neg, tok_of_slot,
                                     cnt, out + (size_t)NTOK*DDIM);

  // R2 grid orientation: x = coltile, y = rowtile
  ffn_mfma<1><<<dim3(HDIM/128, ECAP/128), 256, 0, stream>>>(
      xbf, W1t, b1, tok_of_slot, cnt, gate_value, (void*)hbf);
  ffn_mfma<2><<<dim3(DDIM/128, ECAP/128), 256, 0, stream>>>(
      hbf, W2t, b2, tok_of_slot, cnt, gate_value, (void*)out);

  passthrough_kernel<<<NTOK, 256, 0, stream>>>(x, slot_or_neg, gate_value, out);
}